// Round 2
// baseline (138.607 us; speedup 1.0000x reference)
//
#include <hip/hip_runtime.h>

#define B_ 64
#define S_ 512
#define H_ 768
#define L_ 9
#define EMP 12                  // padded emission row stride (floats)
#define NCH 64                  // chunks per batch
#define CVEC 21                 // float4 records per chunk matrix (84 floats)

// ---------------------------------------------------------------------------
// Kernel A: emissions = hidden @ W + b, layout em[t][b][EMP], masked rows skipped
// ---------------------------------------------------------------------------
__global__ __launch_bounds__(256) void emis_kernel(
    const float* __restrict__ hidden, const float* __restrict__ W,
    const float* __restrict__ bias, const int* __restrict__ lengths,
    float* __restrict__ em)
{
    const int lane = threadIdx.x & 63;
    const int wave = (blockIdx.x << 2) + (threadIdx.x >> 6);
    const int row0 = wave << 2;              // 4 consecutive rows, same batch
    const int b = row0 >> 9;
    int len = lengths[b]; if (len < 1) len = 1;
    const int s0 = row0 & 511;
    if (s0 >= len) return;                   // all 4 rows masked -> skip W load

    // W columns for this lane's k-set: k = 256*j + 4*lane + d
    float Wreg[12][9];
    #pragma unroll
    for (int j = 0; j < 3; ++j)
        #pragma unroll
        for (int d = 0; d < 4; ++d) {
            const int k = 256 * j + 4 * lane + d;
            #pragma unroll
            for (int l = 0; l < 9; ++l)
                Wreg[j * 4 + d][l] = W[k * 9 + l];
        }
    const float bl = (lane < 9) ? bias[lane] : 0.0f;

    #pragma unroll
    for (int rr = 0; rr < 4; ++rr) {
        const int s = s0 + rr;
        if (s >= len) continue;
        const int row = row0 + rr;

        const float4* h4 = (const float4*)(hidden + (size_t)row * H_);
        float acc[9];
        #pragma unroll
        for (int l = 0; l < 9; ++l) acc[l] = 0.0f;

        #pragma unroll
        for (int j = 0; j < 3; ++j) {
            float4 h = h4[j * 64 + lane];
            const float* hp = &h.x;
            #pragma unroll
            for (int d = 0; d < 4; ++d) {
                const float hv = hp[d];
                #pragma unroll
                for (int l = 0; l < 9; ++l)
                    acc[l] = fmaf(hv, Wreg[j * 4 + d][l], acc[l]);
            }
        }
        #pragma unroll
        for (int off = 32; off >= 1; off >>= 1)
            #pragma unroll
            for (int l = 0; l < 9; ++l)
                acc[l] += __shfl_xor(acc[l], off, 64);

        float v = acc[0];
        #pragma unroll
        for (int l = 1; l < 9; ++l)
            if (lane == l) v = acc[l];
        if (lane < 9)
            em[(size_t)(s * 64 + b) * EMP + lane] = v + bl;
    }
}

// ---------------------------------------------------------------------------
// Kernel B: per-(batch,chunk) 9x9 transfer-matrix product (8 timesteps/chunk).
// Block = chunk c, lane = batch b. Masked steps are identity.
// Cm layout: float4 [(c*CVEC + q)*64 + b]; record = 81 matrix + logscale + pad.
// ---------------------------------------------------------------------------
__global__ __launch_bounds__(64, 1) void chunk_kernel(
    const float* __restrict__ em, const float* __restrict__ trans,
    const int* __restrict__ lengths, float4* __restrict__ Cm4)
{
    const int b = threadIdx.x;
    const int c = blockIdx.x;
    int len = lengths[b]; if (len < 1) len = 1;

    float P[81];
    #pragma unroll
    for (int m = 0; m < 81; ++m) P[m] = __expf(trans[m]);

    float A[81];
    const int t0 = 8 * c + 1;

    float e[9];
    if (t0 < len) {
        const float4* p = (const float4*)(em + (size_t)(t0 * 64 + b) * EMP);
        float4 v0 = p[0], v1 = p[1], v2 = p[2];
        e[0]=__expf(v0.x); e[1]=__expf(v0.y); e[2]=__expf(v0.z); e[3]=__expf(v0.w);
        e[4]=__expf(v1.x); e[5]=__expf(v1.y); e[6]=__expf(v1.z); e[7]=__expf(v1.w);
        e[8]=__expf(v2.x);
        #pragma unroll
        for (int i = 0; i < 9; ++i)
            #pragma unroll
            for (int j = 0; j < 9; ++j)
                A[i * 9 + j] = P[i * 9 + j] * e[j];
    } else {
        #pragma unroll
        for (int i = 0; i < 9; ++i)
            #pragma unroll
            for (int j = 0; j < 9; ++j)
                A[i * 9 + j] = (i == j) ? 1.0f : 0.0f;
    }

    #pragma unroll
    for (int s = 1; s < 8; ++s) {
        const int t = t0 + s;
        if (t < 512 && t < len) {
            const float4* p = (const float4*)(em + (size_t)(t * 64 + b) * EMP);
            float4 v0 = p[0], v1 = p[1], v2 = p[2];
            e[0]=__expf(v0.x); e[1]=__expf(v0.y); e[2]=__expf(v0.z); e[3]=__expf(v0.w);
            e[4]=__expf(v1.x); e[5]=__expf(v1.y); e[6]=__expf(v1.z); e[7]=__expf(v1.w);
            e[8]=__expf(v2.x);
            #pragma unroll
            for (int i = 0; i < 9; ++i) {
                float r0=A[i*9+0], r1=A[i*9+1], r2=A[i*9+2], r3=A[i*9+3],
                      r4=A[i*9+4], r5=A[i*9+5], r6=A[i*9+6], r7=A[i*9+7], r8=A[i*9+8];
                #pragma unroll
                for (int j = 0; j < 9; ++j) {
                    float sum = r0 * P[0*9+j];
                    sum = fmaf(r1, P[1*9+j], sum);
                    sum = fmaf(r2, P[2*9+j], sum);
                    sum = fmaf(r3, P[3*9+j], sum);
                    sum = fmaf(r4, P[4*9+j], sum);
                    sum = fmaf(r5, P[5*9+j], sum);
                    sum = fmaf(r6, P[6*9+j], sum);
                    sum = fmaf(r7, P[7*9+j], sum);
                    sum = fmaf(r8, P[8*9+j], sum);
                    A[i * 9 + j] = sum * e[j];
                }
            }
        }
    }

    float mx = A[0];
    #pragma unroll
    for (int m = 1; m < 81; ++m) mx = fmaxf(mx, A[m]);
    const float r = 1.0f / mx;
    const float lg = __logf(mx);

    #pragma unroll
    for (int q = 0; q < 21; ++q) {
        float4 v;
        const int k0 = 4 * q;
        v.x = (k0+0 < 81) ? A[(k0+0)<81?k0+0:0] * r : ((k0+0 == 81) ? lg : 0.0f);
        v.y = (k0+1 < 81) ? A[(k0+1)<81?k0+1:0] * r : ((k0+1 == 81) ? lg : 0.0f);
        v.z = (k0+2 < 81) ? A[(k0+2)<81?k0+2:0] * r : ((k0+2 == 81) ? lg : 0.0f);
        v.w = (k0+3 < 81) ? A[(k0+3)<81?k0+3:0] * r : ((k0+3 == 81) ? lg : 0.0f);
        Cm4[((size_t)c * CVEC + q) * 64 + b] = v;
    }
}

// ---------------------------------------------------------------------------
// Kernel C: block = batch. Wave 0: alpha scan over 64 chunk matrices
// (double-buffered). Wave 1: gold-path numerator (lane-strided over t).
// ---------------------------------------------------------------------------
#define LOADC(dst, cc)                                                        \
    do {                                                                      \
        _Pragma("unroll")                                                     \
        for (int q = 0; q < 21; ++q) {                                        \
            float4 v = Cm4[((size_t)(cc) * CVEC + q) * 64 + b];               \
            dst[4*q+0] = v.x; dst[4*q+1] = v.y;                               \
            dst[4*q+2] = v.z; dst[4*q+3] = v.w;                               \
        }                                                                     \
    } while (0)

#define STEPC(Cf)                                                             \
    do {                                                                      \
        float an[9];                                                          \
        _Pragma("unroll")                                                     \
        for (int j = 0; j < 9; ++j) {                                         \
            float s = alpha[0] * Cf[j];                                       \
            _Pragma("unroll")                                                 \
            for (int i = 1; i < 9; ++i) s = fmaf(alpha[i], Cf[i*9+j], s);     \
            an[j] = s;                                                        \
        }                                                                     \
        float m2 = an[0];                                                     \
        _Pragma("unroll")                                                     \
        for (int j = 1; j < 9; ++j) m2 = fmaxf(m2, an[j]);                    \
        logZ += Cf[81] + __logf(m2);                                          \
        const float rr_ = 1.0f / m2;                                          \
        _Pragma("unroll")                                                     \
        for (int j = 0; j < 9; ++j) alpha[j] = an[j] * rr_;                   \
    } while (0)

__global__ __launch_bounds__(128, 1) void final_kernel(
    const float* __restrict__ em, const float4* __restrict__ Cm4,
    const int* __restrict__ labels, const int* __restrict__ lengths,
    const float* __restrict__ start_t, const float* __restrict__ trans,
    const float* __restrict__ end_t, float* __restrict__ out)
{
    const int b = blockIdx.x;
    const int wid = threadIdx.x >> 6, lane = threadIdx.x & 63;
    int len = lengths[b]; if (len < 1) len = 1;

    if (wid == 0) {
        // ---- denominator: alpha0 then 64 chunk-matrix steps ----
        const float4* e0 = (const float4*)(em + (size_t)b * EMP);
        float4 v0 = e0[0], v1 = e0[1], v2 = e0[2];
        float al[9] = { v0.x + start_t[0], v0.y + start_t[1], v0.z + start_t[2],
                        v0.w + start_t[3], v1.x + start_t[4], v1.y + start_t[5],
                        v1.z + start_t[6], v1.w + start_t[7], v2.x + start_t[8] };
        float m0 = al[0];
        #pragma unroll
        for (int j = 1; j < 9; ++j) m0 = fmaxf(m0, al[j]);
        float alpha[9];
        #pragma unroll
        for (int j = 0; j < 9; ++j) alpha[j] = __expf(al[j] - m0);
        float logZ = m0;

        float Ca[84], Cb[84];
        LOADC(Ca, 0);
        #pragma unroll 1
        for (int c = 0; c < 62; c += 2) {
            LOADC(Cb, c + 1);
            STEPC(Ca);
            LOADC(Ca, c + 2);
            STEPC(Cb);
        }
        LOADC(Cb, 63);
        STEPC(Ca);
        STEPC(Cb);

        float ev = 0.0f;
        #pragma unroll
        for (int j = 0; j < 9; ++j) ev = fmaf(alpha[j], __expf(end_t[j]), ev);
        if (lane == 0) atomicAdd(out, logZ + __logf(ev));
    } else {
        // ---- numerator ----
        const int* lab = labels + (size_t)b * S_;
        float part = 0.0f;
        for (int t = 1 + lane; t < len; t += 64) {
            const int tp = lab[t - 1], tc = lab[t];
            part += trans[tp * 9 + tc] + em[(size_t)(t * 64 + b) * EMP + tc];
        }
        #pragma unroll
        for (int off = 32; off >= 1; off >>= 1) part += __shfl_xor(part, off, 64);
        if (lane == 0) {
            const int l0 = lab[0], le = lab[len - 1];
            const float num = start_t[l0] + em[(size_t)b * EMP + l0] + part + end_t[le];
            atomicAdd(out, -num);
        }
    }
}

// ---------------------------------------------------------------------------
extern "C" void kernel_launch(void* const* d_in, const int* in_sizes, int n_in,
                              void* d_out, int out_size, void* d_ws, size_t ws_size,
                              hipStream_t stream)
{
    (void)in_sizes; (void)n_in; (void)out_size; (void)ws_size;
    const float* hidden  = (const float*)d_in[0];
    const float* W       = (const float*)d_in[1];
    const float* bias    = (const float*)d_in[2];
    const float* start_t = (const float*)d_in[3];
    const float* trans   = (const float*)d_in[4];
    const float* end_t   = (const float*)d_in[5];
    const int*   labels  = (const int*)d_in[6];
    const int*   lengths = (const int*)d_in[7];

    float*  em  = (float*)d_ws;                       // 512*64*12 floats
    float4* Cm4 = (float4*)(em + (size_t)S_ * 64 * EMP);
    float*  out = (float*)d_out;

    hipMemsetAsync(out, 0, sizeof(float), stream);
    emis_kernel<<<2048, 256, 0, stream>>>(hidden, W, bias, lengths, em);
    chunk_kernel<<<NCH, 64, 0, stream>>>(em, trans, lengths, Cm4);
    final_kernel<<<B_, 128, 0, stream>>>(em, Cm4, labels, lengths,
                                         start_t, trans, end_t, out);
}